// Round 9
// baseline (119.260 us; speedup 1.0000x reference)
//
#include <hip/hip_runtime.h>
#include <math.h>

#define BB 4
#define LL 512
#define EMB 256
#define NH 8
#define HD 32
#define NB_ 3
#define CCN 10
#define NBKT 32
#define SCALE 0.17677669529663687f

typedef __bf16 bf16_t;
typedef __attribute__((ext_vector_type(8))) bf16_t bf16x8;
typedef __attribute__((ext_vector_type(4))) float f32x4;

__device__ __forceinline__ unsigned short f2b(float f) {
    unsigned int u = __float_as_uint(f);
    u += 0x7FFF + ((u >> 16) & 1);   // RNE
    return (unsigned short)(u >> 16);
}
__device__ __forceinline__ float b2f(unsigned short s) {
    return __uint_as_float(((unsigned int)s) << 16);
}
__device__ __forceinline__ unsigned pack2(float a, float b) {
    return (unsigned)f2b(a) | ((unsigned)f2b(b) << 16);
}
__device__ __forceinline__ int bm_of(int tq, int tk) {
    return (tq * tk != 0) ? ((tq - 1) * 3 + tk) : 0;
}
__device__ __forceinline__ unsigned long long shfl_up64(unsigned long long v, int d) {
    unsigned lo = (unsigned)__shfl_up((int)(unsigned)v, d, 64);
    unsigned hi = (unsigned)__shfl_up((int)(v >> 32), d, 64);
    return (((unsigned long long)hi) << 32) | lo;
}

// Stable counting sort of 512 tokens by type (4 types), 256 threads.
__device__ __forceinline__ void sort512(const int* __restrict__ tsb, int* spk,
                                        unsigned long long* wtll, int* msc, int tid) {
    int ty0 = tsb[2 * tid], ty1 = tsb[2 * tid + 1];
    unsigned long long pk = (1ULL << (16 * ty0)) + (1ULL << (16 * ty1));
    unsigned long long v = pk;
    int lane = tid & 63;
#pragma unroll
    for (int off = 1; off < 64; off <<= 1) {
        unsigned long long o = shfl_up64(v, off);
        if (lane >= off) v += o;
    }
    int w = tid >> 6;
    if (lane == 63) wtll[w] = v;
    __syncthreads();
    unsigned long long pre = 0, tot = 0;
#pragma unroll
    for (int i = 0; i < 4; i++) {
        unsigned long long xx = wtll[i];
        if (i < w) pre += xx;
        tot += xx;
    }
    v += pre;
    unsigned long long excl = v - pk;
    int c0 = (int)(tot & 0xFFFF), c1 = (int)((tot >> 16) & 0xFFFF);
    int c2 = (int)((tot >> 32) & 0xFFFF), c3 = (int)((tot >> 48) & 0xFFFF);
    int ub0 = 0, ub1 = c0, ub2 = c0 + c1, ub3 = c0 + c1 + c2;
    if (tid == 0) {
        int pc0 = (c0 + 31) & ~31, pc1 = (c1 + 31) & ~31, pc2 = (c2 + 31) & ~31, pc3 = (c3 + 31) & ~31;
        int pb1 = pc0, pb2 = pc0 + pc1, pb3 = pc0 + pc1 + pc2;
        msc[0] = 0;  msc[1] = pb1; msc[2] = pb2; msc[3] = pb3;
        msc[4] = ub0; msc[5] = ub1; msc[6] = ub2; msc[7] = ub3;
        msc[8] = c0; msc[9] = c1; msc[10] = c2; msc[11] = c3;
        msc[12] = (pb3 + pc3 + 63) & ~63;
    }
    int bases[4] = {ub0, ub1, ub2, ub3};
    int r0 = (int)((excl >> (16 * ty0)) & 0xFFFF);
    unsigned long long excl1 = excl + (1ULL << (16 * ty0));
    int r1 = (int)((excl1 >> (16 * ty1)) & 0xFFFF);
    spk[bases[ty0] + r0] = (ty0 << 16) | (2 * tid);
    spk[bases[ty1] + r1] = (ty1 << 16) | (2 * tid + 1);
    __syncthreads();
}

__device__ __forceinline__ void pad_lookup(const int* msc, int pos, int& real, int& upos, int& seg) {
    seg = (pos >= msc[1]) + (pos >= msc[2]) + (pos >= msc[3]);
    int r = pos - msc[seg];
    real = (r < msc[8 + seg]) ? 1 : 0;
    upos = msc[4 + seg] + r;
}

// ---------------- K1 (merged): QKV (g<768, self-sort + direct strided f32 W reads, 64-col blocks)
// + alpha-combine (768<=g<928) + mask scan (928<=g<992, 64 blocks, plain flag stores)
// + sort-out (992<=g<996) + bucket table (g==996). ----------------
__global__ __launch_bounds__(256, 4) void k_main(
    const float* __restrict__ x, const int* __restrict__ ts,
    const float* __restrict__ Wq, const float* __restrict__ Wk, const float* __restrict__ Wv,
    const float* __restrict__ A1, const float* __restrict__ W1,
    const float* __restrict__ A2, const float* __restrict__ W2,
    const float* __restrict__ am,
    float* __restrict__ W1s, float* __restrict__ W2s,
    unsigned short* __restrict__ W1Tb, unsigned short* __restrict__ W2Tb,
    int* __restrict__ mfl,
    int* __restrict__ spkg, int* __restrict__ mscg, int* __restrict__ kpadg,
    short* __restrict__ tblg,
    unsigned short* __restrict__ qp, unsigned short* __restrict__ kp,
    unsigned short* __restrict__ vpT) {
    __shared__ int spk[LL];
    __shared__ unsigned long long wtll[4];
    __shared__ int msc[16];
    __shared__ __align__(16) unsigned short vt_l[64 * 33];

    int g = blockIdx.x, tid = threadIdx.x;

    if (g >= 768) {
        int gg = g - 768;
        if (gg < 160) {  // alpha-combine (consumed by k_attn, next launch)
            float* cmbf = (float*)vt_l;  // 4224 B == vt_l size
            int idx = gg;
            const float* alpha = (idx < 80) ? A1 : A2;
            const float* W     = (idx < 80) ? W1 : W2;
            float* Ws          = (idx < 80) ? W1s : W2s;
            unsigned short* WT = (idx < 80) ? W1Tb : W2Tb;
            idx %= 80;
            int cc = idx / NH, h = idx % NH;
            float a0 = alpha[cc * NB_ * NH + 0 * NH + h];
            float a1 = alpha[cc * NB_ * NH + 1 * NH + h];
            float a2 = alpha[cc * NB_ * NH + 2 * NH + h];
            float mx = fmaxf(a0, fmaxf(a1, a2));
            float e0 = __expf(a0 - mx), e1 = __expf(a1 - mx), e2 = __expf(a2 - mx);
            float inv = 1.0f / (e0 + e1 + e2);
            e0 *= inv; e1 *= inv; e2 *= inv;
            for (int i = tid; i < HD * HD; i += 256) {
                int m = i >> 5, n = i & 31;
                float acc = e0 * W[((0 * NH + h) * HD + m) * HD + n]
                          + e1 * W[((1 * NH + h) * HD + m) * HD + n]
                          + e2 * W[((2 * NH + h) * HD + m) * HD + n];
                cmbf[m * 33 + n] = acc;
            }
            __syncthreads();
            for (int i = tid; i < HD * HD; i += 256) {
                int a = i >> 5, bq = i & 31;
                Ws[((cc * NH + h) * HD + a) * HD + bq] = cmbf[a * 33 + bq];
                WT[((size_t)(cc * NH + h) * HD + a) * HD + bq] = f2b(cmbf[bq * 33 + a]);
            }
            return;
        }
        if (gg < 224) {  // mask scan: 64 blocks, per-block flag, plain store (no init needed)
            int* reds = (int*)wtll;
            int idx = gg - 160;
            const uint4* p = (const uint4*)am + (size_t)idx * 4096;
            unsigned o = 0;
#pragma unroll
            for (int j = 0; j < 16; j++) {
                uint4 v = p[tid + j * 256];
                o |= v.x | v.y | v.z | v.w;
            }
            int wv = __any(o != 0);
            if ((tid & 63) == 0) reds[tid >> 6] = wv;
            __syncthreads();
            if (tid == 0) mfl[idx] = reds[0] | reds[1] | reds[2] | reds[3];
            return;
        }
        if (gg < 228) {  // sort-out: spkg/mscg/kpadg for k_attn
            int b = gg - 224;
            sort512(ts + b * LL, spk, wtll, msc, tid);
            for (int i = tid; i < LL; i += 256) spkg[b * LL + i] = spk[i];
            if (tid < 16) mscg[b * 16 + tid] = msc[tid];
            int KT = msc[12];
            for (int pos = tid; pos < KT; pos += 256) {
                int real, upos, seg;
                pad_lookup(msc, pos, real, upos, seg);
                int orig = real ? (spk[upos] & 0xFFFF) : 0x3FF;
                kpadg[b * 640 + pos] = (seg << 20) | ((real ? upos : 0) << 10) | orig;
            }
            return;
        }
        // bucket table
        for (int d = tid; d < LL; d += 256) {
            int v;
            if (d < 8) v = d;
            else {
                double r = log((double)d / 8.0) / log(5.0);
                v = 8 + (int)(r * 8.0);
                if (v > 15) v = 15;
            }
            tblg[d] = (short)v;
        }
        return;
    }

    // ---------------- QKV block: 64 output columns (quarter nq of one of q/k/v) ----------------
    int ns = g % 12, gb = g / 12;
    int b = gb >> 4, tb = gb & 15, i0 = tb * 32;
    int which = ns >> 2, nq = ns & 3;
    int wave = tid >> 6, lane = tid & 63, quad = lane >> 4, col = lane & 15;

    // self-sort (deterministic; identical to sort-out blocks' result)
    sort512(ts + b * LL, spk, wtll, msc, tid);

    bf16x8 afr[2][8];
#pragma unroll
    for (int mt = 0; mt < 2; mt++) {
        int orig = spk[i0 + mt * 16 + col] & 0xFFFF;
        const float* xr = &x[(size_t)(b * LL + orig) * EMB];
#pragma unroll
        for (int kc = 0; kc < 8; kc++) {
            float4 v0 = *(const float4*)&xr[kc * 32 + quad * 8];
            float4 v1 = *(const float4*)&xr[kc * 32 + quad * 8 + 4];
            uint4 up;
            up.x = pack2(v0.x, v0.y); up.y = pack2(v0.z, v0.w);
            up.z = pack2(v1.x, v1.y); up.w = pack2(v1.z, v1.w);
            afr[mt][kc] = *(bf16x8*)&up;
        }
    }
    int t_start = spk[i0] >> 16, t_end = spk[i0 + 31] >> 16;
    unsigned short* outp = (which == 0) ? qp : kp;
    const float* wmat = (which == 0) ? Wq : (which == 1) ? Wk : Wv;

    int n_0 = nq * 64 + wave * 16 + col;   // this lane's output column

    for (int ty = t_start; ty <= t_end; ty++) {
        const float* wty = wmat + (size_t)ty * EMB * EMB;
        // per-lane strided column base: element j of kc-fragment = wc0[kc*32*EMB + j*EMB]
        const float* wc0 = wty + (size_t)(quad * 8) * EMB + n_0;
        f32x4 acc[2];
        acc[0] = (f32x4){0.f, 0.f, 0.f, 0.f};
        acc[1] = (f32x4){0.f, 0.f, 0.f, 0.f};
#pragma unroll
        for (int kc = 0; kc < 8; kc++) {
            const float* p0 = wc0 + (size_t)kc * 32 * EMB;
            float f0[8];
#pragma unroll
            for (int j = 0; j < 8; j++) f0[j] = p0[j * EMB];
            uint4 u0;
            u0.x = pack2(f0[0], f0[1]); u0.y = pack2(f0[2], f0[3]);
            u0.z = pack2(f0[4], f0[5]); u0.w = pack2(f0[6], f0[7]);
            bf16x8 b0 = *(bf16x8*)&u0;
            acc[0] = __builtin_amdgcn_mfma_f32_16x16x32_bf16(afr[0][kc], b0, acc[0], 0, 0, 0);
            acc[1] = __builtin_amdgcn_mfma_f32_16x16x32_bf16(afr[1][kc], b0, acc[1], 0, 0, 0);
        }
        if (which < 2) {
#pragma unroll
            for (int mt = 0; mt < 2; mt++)
#pragma unroll
                for (int r = 0; r < 4; r++) {
                    int tokloc = mt * 16 + quad * 4 + r;
                    int tty = spk[i0 + tokloc] >> 16;
                    if (tty != ty) continue;
                    int h = n_0 >> 5, d = n_0 & 31;
                    outp[((size_t)(b * NH + h) * LL + i0 + tokloc) * HD + d] = f2b(acc[mt][r]);
                }
        } else {
            int ln = wave * 16 + col;
#pragma unroll
            for (int mt = 0; mt < 2; mt++)
#pragma unroll
                for (int r = 0; r < 4; r++)
                    vt_l[ln * 33 + mt * 16 + quad * 4 + r] = f2b(acc[mt][r]);
            __syncthreads();
            int ub = msc[4 + ty], cnt = msc[8 + ty], pb = msc[ty];
            int lo = ub - i0; if (lo < 0) lo = 0;
            int hi = ub + cnt - i0; if (hi > 32) hi = 32;
            int run = hi - lo;
            int pbase = pb + i0 + lo - ub;
            int rowbase = b * 256 + nq * 64;
            int t32 = tid & 31;
            if (t32 < run) {
                for (int rr = tid >> 5; rr < 64; rr += 8)
                    vpT[(size_t)(rowbase + rr) * 640 + pbase + t32] = vt_l[rr * 33 + lo + t32];
            }
            __syncthreads();
        }
    }
}

// ---------------- K2: attention core, 512 threads / 8 waves (fused softmax when mask==0) ----------------
#define SCP 648
#define OFF_UN   20736
#define OFF_QTB  29184
#define OFF_KPAD 33536
#define OFF_TBL  36096
#define OFF_RPL  37120
#define OFF_QOR  38400
#define OFF_QTY  38464
#define OFF_INV  38528
#define OFF_PSUM 38592
#define SM_TOTAL 39104
__global__ __launch_bounds__(512, 8) void k_attn(
    const unsigned short* __restrict__ qp, const unsigned short* __restrict__ kp,
    const unsigned short* __restrict__ vpT,
    const int* __restrict__ spkg, const int* __restrict__ mscg, const int* __restrict__ kpadg,
    const short* __restrict__ tblg,
    const float* __restrict__ rp, const float* __restrict__ am,
    const float* __restrict__ W1s, const float* __restrict__ W2s,
    const unsigned short* __restrict__ W1Tb, const unsigned short* __restrict__ W2Tb,
    const int* __restrict__ mfl, float* __restrict__ ctx) {
    __shared__ __align__(16) char smem[SM_TOTAL];
    __shared__ int msk_s;
    unsigned short* scu = (unsigned short*)smem;
    unsigned short* qstb = (unsigned short*)(smem + OFF_UN);   // [16*40]
    float* sb   = (float*)(smem + OFF_UN);                     // [16*132] (aliases qstb, dead after qt)
    unsigned short* qtb = (unsigned short*)(smem + OFF_QTB);   // [16*136] / later sbb
    unsigned short* sbb = (unsigned short*)(smem + OFF_QTB);
    int*   kpad = (int*)(smem + OFF_KPAD);                     // [640]
    short* tbl  = (short*)(smem + OFF_TBL);
    float* rp_l = (float*)(smem + OFF_RPL);
    int*   qor_l = (int*)(smem + OFF_QOR);
    int*   qty_l = (int*)(smem + OFF_QTY);
    float* inv_l = (float*)(smem + OFF_INV);
    float* psum = (float*)(smem + OFF_PSUM);                   // [128] per-wave row sums

    int blk = blockIdx.x;
    int b = blk >> 8, h = (blk >> 5) & 7, q16 = blk & 31;
    int i0q = q16 * 16;
    int tid = threadIdx.x;
    int wave = tid >> 6, lane = tid & 63, quad = lane >> 4, col = lane & 15;
    int bh = b * NH + h;

    int KT = mscg[b * 16 + 12];
    if (wave == 0) {
        int v = mfl[lane];
        int anyv = __any(v != 0);
        if (lane == 0) msk_s = anyv;
    }
    if (tid < 16) {
        int v = spkg[b * LL + i0q + tid];
        qor_l[tid] = v & 0xFFFF; qty_l[tid] = v >> 16;
    }
    if (tid < (KT >> 2)) ((int4*)kpad)[tid] = ((const int4*)(kpadg + b * 640))[tid];
    if (tid < 256) ((int*)tbl)[tid] = ((const int*)tblg)[tid];   // 512 shorts = 256 ints
    for (int i = tid; i < CCN * NBKT; i += 512) rp_l[i] = rp[i * NH + h];
    if (tid < 256) {   // stage 16 q rows (bf16, pitch 40)
        int q = tid >> 4, m2 = (tid & 15) * 2;
        ((unsigned*)qstb)[q * 20 + (tid & 15)] =
            *(const unsigned*)&qp[((size_t)bh * LL + i0q + q) * HD + m2];
    }
    __syncthreads();

    int qor_r[4], qty_r[4];
#pragma unroll
    for (int r = 0; r < 4; r++) { qor_r[r] = qor_l[quad * 4 + r]; qty_r[r] = qty_l[quad * 4 + r]; }
    bool uniq = (qty_l[0] == qty_l[15]);
    int tqu = qty_l[0];
    // tokens are sorted by type, so a 16-row tile is almost always 1 or 2 contiguous types
    int tA = qty_l[0], tB = qty_l[15];
    bool two = false;
    if (!uniq) {
        two = true;
#pragma unroll
        for (int i = 0; i < 16; i++) {
            int t = qty_l[i];
            two = two && (t == tA || t == tB);
        }
    }
    int mz = (msk_s == 0);

    // ---- qt: 8 sub-problems, one per wave ----
    if (uniq) {
        int tk = wave >> 1, nhf = wave & 1;
        int bmv = bm_of(tqu, tk);
        bf16x8 a = *(const bf16x8*)&qstb[col * 40 + quad * 8];
        bf16x8 bb = *(const bf16x8*)&W1Tb[((size_t)(bmv * NH + h) * HD + nhf * 16 + col) * HD + quad * 8];
        f32x4 d = {0.f, 0.f, 0.f, 0.f};
        d = __builtin_amdgcn_mfma_f32_16x16x32_bf16(a, bb, d, 0, 0, 0);
#pragma unroll
        for (int r = 0; r < 4; r++)
            qtb[(quad * 4 + r) * 136 + tk * 32 + nhf * 16 + col] = f2b(d[r]);
    } else if (two) {
        int tk = wave >> 1, nhf = wave & 1;
        bf16x8 a = *(const bf16x8*)&qstb[col * 40 + quad * 8];
        bf16x8 bA = *(const bf16x8*)&W1Tb[((size_t)(bm_of(tA, tk) * NH + h) * HD + nhf * 16 + col) * HD + quad * 8];
        bf16x8 bBv = *(const bf16x8*)&W1Tb[((size_t)(bm_of(tB, tk) * NH + h) * HD + nhf * 16 + col) * HD + quad * 8];
        f32x4 dA = {0.f, 0.f, 0.f, 0.f};
        f32x4 dB = {0.f, 0.f, 0.f, 0.f};
        dA = __builtin_amdgcn_mfma_f32_16x16x32_bf16(a, bA, dA, 0, 0, 0);
        dB = __builtin_amdgcn_mfma_f32_16x16x32_bf16(a, bBv, dB, 0, 0, 0);
#pragma unroll
        for (int r = 0; r < 4; r++) {
            float val = (qty_r[r] == tA) ? dA[r] : dB[r];
            qtb[(quad * 4 + r) * 136 + tk * 32 + nhf * 16 + col] = f2b(val);
        }
    } else {
        for (int i = tid; i < 16 * 128; i += 512) {
            int q = i >> 7, r = i & 127, tk = r >> 5, n = r & 31;
            int bmv = bm_of(qty_l[q], tk);
            const float* wb = &W1s[((bmv * NH + h) * HD) * HD + n];
            float acc = 0.f;
#pragma unroll
            for (int m = 0; m < HD; m++) acc += b2f(qstb[q * 40 + m]) * wb[m * HD];
            qtb[q * 136 + tk * 32 + n] = f2b(acc);
        }
    }
    __syncthreads();

    // ---- pass 1: scores, tiles strided across 8 waves ----
    const float* amb = am + (size_t)b * LL * LL;
    int ntiles = KT >> 4;
    if (mz) {
        float rs[4] = {0.f, 0.f, 0.f, 0.f};
        int tqm_r[4], tqz_r[4];
#pragma unroll
        for (int r = 0; r < 4; r++) { tqm_r[r] = (qty_r[r] - 1) * 3; tqz_r[r] = (qty_r[r] != 0); }
        for (int tile = wave; tile < ntiles; tile += 8) {
            int kb = tile * 16;
            int kv0 = kpad[kb];
            if ((kv0 & 0x3FF) == 0x3FF) {
#pragma unroll
                for (int r = 0; r < 4; r++) scu[(quad * 4 + r) * SCP + kb + col] = 0;
                continue;
            }
            int tkt = kv0 >> 20;
            int kpi = kb + col;
            int kv = kpad[kpi];
            int ko = kv & 0x3FF;
            int upos = (kv >> 10) & 0x3FF;
            bool real = (ko != 0x3FF);
            bf16x8 bfr;
            if (real) bfr = *(const bf16x8*)&kp[((size_t)bh * LL + upos) * HD + quad * 8];
            else { uint4 z = make_uint4(0, 0, 0, 0); bfr = *(bf16x8*)&z; }
            bf16x8 a = *(const bf16x8*)&qtb[col * 136 + tkt * 32 + quad * 8];
            f32x4 d = {0.f, 0.f, 0.f, 0.f};
            d = __builtin_amdgcn_mfma_f32_16x16x32_bf16(a, bfr, d, 0, 0, 0);
            if (!real) {
#pragma unroll
                for (int r = 0; r < 4; r++) scu[(quad * 4 + r) * SCP + kpi] = 0;
            } else {
#pragma unroll
                for (int r = 0; r < 4; r++) {
                    int q = quad * 4 + r;
                    int qo = qor_r[r];
                    int dd = qo - ko;
                    int ad = dd < 0 ? -dd : dd;
                    int bk = (dd < 0 ? 16 : 0) + (int)tbl[ad];
                    int bmv = (tqz_r[r] && tkt) ? tqm_r[r] + tkt : 0;
                    float sv = d[r] * SCALE + rp_l[bmv * NBKT + bk];
                    float e = __expf(sv);
                    scu[q * SCP + kpi] = f2b(e);
                    rs[r] += e;
                }
            }
        }
#pragma unroll
        for (int off = 1; off < 16; off <<= 1) {
#pragma unroll
            for (int r = 0; r < 4; r++) rs[r] += __shfl_xor(rs[r], off, 16);
        }
        if (col == 0) {
#pragma unroll
            for (int r = 0; r < 4; r++) psum[wave * 16 + quad * 4 + r] = rs[r];
        }
    } else {
        for (int tile = wave; tile < ntiles; tile += 8) {
            int kb = tile * 16;
            int kv0 = kpad[kb];
            if ((kv0 & 0x3FF) == 0x3FF) {
#pragma unroll
                for (int r = 0; r < 4; r++) scu[(quad * 4 + r) * SCP + kb + col] = 0xFF80;
                continue;
            }
            int tkt = kv0 >> 20;
            int kpi = kb + col;
            int kv = kpad[kpi];
            int ko = kv & 0x3FF;
            int upos = (kv >> 10) & 0x3FF;
            bool real = (ko != 0x3FF);
            bf16x8 bfr;
            if (real) bfr = *(const bf16x8*)&kp[((size_t)bh * LL + upos) * HD + quad * 8];
            else { uint4 z = make_uint4(0, 0, 0, 0); bfr = *(bf16x8*)&z; }
            bf16x8 a = *(const bf16x8*)&qtb[col * 136 + tkt * 32 + quad * 8];
            f32x4 d = {0.f, 0.f, 0.f, 0.f};
            d = __builtin_amdgcn_mfma_f32_16x16x32_bf16(a, bfr, d, 0, 0, 0);
            if (!real) {
#pragma unroll
                for (int r = 0; r < 4; r++) scu[(quad * 4 + r) * SCP + kpi] = 0xFF80;
            } else {
#pragma unroll
                for (int r = 0; r < 4; r++) {
                    int q = quad * 4 + r;
                    int qo = qor_r[r];
                    int dd = qo - ko;
                    int ad = dd < 0 ? -dd : dd;
                    int bk = (dd < 0 ? 16 : 0) + (int)tbl[ad];
                    float sv = d[r] * SCALE + rp_l[bm_of(qty_r[r], tkt) * NBKT + bk];
                    sv += amb[(size_t)qo * LL + ko];
                    scu[q * SCP + kpi] = f2b(sv);
                }
            }
        }
    }
    __syncthreads();

    // ---- pass 2: softmax finish ----
    if (mz) {
        if (tid < 16) {
            float s = 0.f;
#pragma unroll
            for (int w = 0; w < 8; w++) s += psum[w * 16 + tid];
            inv_l[tid] = 1.0f / s;
        }
    } else if (tid < 256) {
        int gq = tid >> 4, t16 = tid & 15;
        float mx = -1e30f;
        for (int kk = t16; kk < KT; kk += 16) mx = fmaxf(mx, b2f(scu[gq * SCP + kk]));
#pragma unroll
        for (int off = 1; off < 16; off <<= 1) mx = fmaxf(mx, __shfl_xor(mx, off, 16));
        float sum = 0.f;
        for (int kk = t16; kk < KT; kk += 16) {
            int idx = gq * SCP + kk;
            float e = __expf(b2f(scu[idx]) - mx);
            scu[idx] = f2b(e); sum += e;
        }
#pragma unroll
        for (int off = 1; off < 16; off <<= 1) sum += __shfl_xor(sum, off, 16);
        if (t16 == 0) inv_l[gq] = 1.0f / sum;
    }
    __syncthreads();

    // ---- pass 3: PV via MFMA; wave pair (seg, seg+4) splits segment seg's 32-groups
    //      (even/odd). Pair-reduce through sb/sbb with one extra barrier. ----
    const unsigned short* vbase = &vpT[(size_t)(b * 256 + h * 32) * 640];
    f32x4 accv[2];
    accv[0] = (f32x4){0.f, 0.f, 0.f, 0.f};
    accv[1] = (f32x4){0.f, 0.f, 0.f, 0.f};
    {
        int seg = wave & 3, halfp = wave >> 2;
        int pb = mscg[b * 16 + seg];         // padded base of segment
        int cnt = mscg[b * 16 + 8 + seg];    // real count of segment
        int g0 = pb >> 5, g1 = (pb + cnt + 31) >> 5;
        for (int gg = g0 + halfp; gg < g1; gg += 2) {
            int loc = gg << 5;
            bf16x8 a = *(const bf16x8*)&scu[col * SCP + loc + quad * 8];
            bf16x8 b0 = *(const bf16x8*)&vbase[(size_t)col * 640 + loc + quad * 8];
            bf16x8 b1 = *(const bf16x8*)&vbase[(size_t)(col + 16) * 640 + loc + quad * 8];
            accv[0] = __builtin_amdgcn_mfma_f32_16x16x32_bf16(a, b0, accv[0], 0, 0, 0);
            accv[1] = __builtin_amdgcn_mfma_f32_16x16x32_bf16(a, b1, accv[1], 0, 0, 0);
        }
    }
    // waves 0-3 deposit partials (sb aliases qstb — dead); waves 4-7 add + emit bf16
    if (wave < 4) {
#pragma unroll
        for (int hh = 0; hh < 2; hh++)
#pragma unroll
            for (int r = 0; r < 4; r++) {
                int q = quad * 4 + r, n = col + 16 * hh;
                sb[q * 132 + wave * 32 + n] = accv[hh][r];
            }
    }
    __syncthreads();
    if (wave >= 4) {
        int seg = wave - 4;
#pragma unroll
        for (int hh = 0; hh < 2; hh++)
#pragma unroll
            for (int r = 0; r < 4; r++) {
                int q = quad * 4 + r, n = col + 16 * hh;
                float fin = sb[q * 132 + seg * 32 + n] + accv[hh][r];
                sb[q * 132 + seg * 32 + n] = fin;
                sbb[q * 136 + seg * 32 + n] = f2b(fin);
            }
    }
    __syncthreads();

    // ---- ctx epilogue ----
    if (uniq) {
        if (wave < 2) {
            int mhf = wave;
            f32x4 d = {0.f, 0.f, 0.f, 0.f};
#pragma unroll
            for (int tk = 0; tk < 4; tk++) {
                int bmv = bm_of(tqu, tk);
                bf16x8 a = *(const bf16x8*)&sbb[col * 136 + tk * 32 + quad * 8];
                bf16x8 bb = *(const bf16x8*)&W2Tb[((size_t)(bmv * NH + h) * HD + mhf * 16 + col) * HD + quad * 8];
                d = __builtin_amdgcn_mfma_f32_16x16x32_bf16(a, bb, d, 0, 0, 0);
            }
#pragma unroll
            for (int r = 0; r < 4; r++) {
                int q = quad * 4 + r;
                ctx[((size_t)(b * LL + qor_l[q])) * EMB + h * HD + mhf * 16 + col] = d[r] * inv_l[q];
            }
        }
    } else if (two) {
        if (wave < 4) {
            // waves 0,1 -> type tA (halves 0,1); waves 2,3 -> type tB (halves 0,1)
            int myT = (wave < 2) ? tA : tB;
            int mhf = wave & 1;
            f32x4 d = {0.f, 0.f, 0.f, 0.f};
#pragma unroll
            for (int tk = 0; tk < 4; tk++) {
                int bmv = bm_of(myT, tk);
                bf16x8 a = *(const bf16x8*)&sbb[col * 136 + tk * 32 + quad * 8];
                bf16x8 bb = *(const bf16x8*)&W2Tb[((size_t)(bmv * NH + h) * HD + mhf * 16 + col) * HD + quad * 8];
                d = __builtin_amdgcn_mfma_f32_16x16x32_bf16(a, bb, d, 0, 0, 0);
            }
#pragma unroll
            for (int r = 0; r < 4; r++) {
                int q = quad * 4 + r;
                if (qty_l[q] == myT)
                    ctx[((size_t)(b * LL + qor_l[q])) * EMB + h * HD + mhf * 16 + col] = d[r] * inv_l[q];
            }
        }
    } else if (tid < 256) {
        int m = tid & 31, qq = tid >> 5;
#pragma unroll
        for (int rep = 0; rep < 2; rep++) {
            int qi = qq + 8 * rep;
            int tq = qty_l[qi];
            float acc = 0.f;
#pragma unroll
            for (int tk2 = 0; tk2 < 4; tk2++) {
                int bmv = bm_of(tq, tk2);
                const float* wb = &W2s[((bmv * NH + h) * HD) * HD + m];
                const float* sbp = &sb[qi * 132 + tk2 * 32];
                for (int n = 0; n < HD; n++) acc += sbp[n] * wb[n * HD];
            }
            int qo = qor_l[qi];
            ctx[((size_t)(b * LL + qo)) * EMB + h * HD + m] = acc * inv_l[qi];
        }
    }
}

// ---------------- K3: residual + LayerNorm (wave-per-token, barrier-free) ----------------
__global__ void k_ln(const float* __restrict__ ctx, const float* __restrict__ x,
                     const float* __restrict__ gamma, const float* __restrict__ beta,
                     float* __restrict__ out) {
    int wave = threadIdx.x >> 6, lane = threadIdx.x & 63;
    int tok = blockIdx.x * 4 + wave;
    size_t base = (size_t)tok * EMB + lane * 4;
    float4 c = *(const float4*)&ctx[base];
    float4 xi = *(const float4*)&x[base];
    float4 v;
    v.x = c.x + xi.x; v.y = c.y + xi.y; v.z = c.z + xi.z; v.w = c.w + xi.w;
    float s = v.x + v.y + v.z + v.w;
    float s2 = v.x * v.x + v.y * v.y + v.z * v.z + v.w * v.w;
#pragma unroll
    for (int off = 1; off < 64; off <<= 1) {
        s += __shfl_xor(s, off, 64);
        s2 += __shfl_xor(s2, off, 64);
    }
    float mu = s * (1.0f / EMB);
    float var = s2 * (1.0f / EMB) - mu * mu;
    float r = rsqrtf(var + 1e-12f);
    float4 gg = *(const float4*)&gamma[lane * 4];
    float4 bb = *(const float4*)&beta[lane * 4];
    float4 o;
    o.x = (v.x - mu) * r * gg.x + bb.x;
    o.y = (v.y - mu) * r * gg.y + bb.y;
    o.z = (v.z - mu) * r * gg.z + bb.z;
    o.w = (v.w - mu) * r * gg.w + bb.w;
    *(float4*)&out[base] = o;
}

extern "C" void kernel_launch(void* const* d_in, const int* in_sizes, int n_in,
                              void* d_out, int out_size, void* d_ws, size_t ws_size,
                              hipStream_t stream) {
    const float* x  = (const float*)d_in[0];
    const float* am = (const float*)d_in[1];
    const int*   ts = (const int*)d_in[2];
    const float* Wq = (const float*)d_in[3];
    const float* Wk = (const float*)d_in[4];
    const float* Wv = (const float*)d_in[5];
    const float* W1 = (const float*)d_in[6];
    const float* a1 = (const float*)d_in[7];
    const float* W2 = (const float*)d_in[8];
    const float* a2 = (const float*)d_in[9];
    const float* rp = (const float*)d_in[10];
    const float* g  = (const float*)d_in[11];
    const float* be = (const float*)d_in[12];
    float* out = (float*)d_out;

    float* ws  = (float*)d_ws;
    float* W1s = ws;                                        // 81920 f
    float* W2s = ws + 81920;                                // -> 163840
    unsigned short* W1Tb = (unsigned short*)(ws + 163840);  // 40960 f
    unsigned short* W2Tb = (unsigned short*)(ws + 204800);  // 40960 f -> 245760
    int* mfl  = (int*)(ws + 245760);                        // 64 mask flags (plain stores, no init)
    int* spkg = (int*)(ws + 246016);                        // 2048 i -> 248064
    int* mscg = (int*)(ws + 248064);                        // 64 i -> 248128
    int* kpadg = (int*)(ws + 248128);                       // 2560 i -> 250688
    short* tblg = (short*)(ws + 250688);                    // 512 s -> 250944
    unsigned short* qp = (unsigned short*)(ws + 250944);
    unsigned short* kp = qp + BB * NH * LL * HD;
    unsigned short* vpT = kp + BB * NH * LL * HD;
    float* ctx = (float*)(vpT + BB * 256 * 640);

    hipLaunchKernelGGL(k_main, dim3(997), dim3(256), 0, stream,
                       x, ts, Wq, Wk, Wv, a1, W1, a2, W2, am,
                       W1s, W2s, W1Tb, W2Tb, mfl, spkg, mscg, kpadg, tblg,
                       qp, kp, vpT);
    hipLaunchKernelGGL(k_attn, dim3(BB * NH * 32), dim3(512), 0, stream,
                       qp, kp, vpT, spkg, mscg, kpadg, tblg, rp, am, W1s, W2s, W1Tb, W2Tb,
                       mfl, ctx);
    hipLaunchKernelGGL(k_ln, dim3(BB * LL / 4), dim3(256), 0, stream, ctx, x, g, be, out);
}

// Round 10
// 116.018 us; speedup vs baseline: 1.0280x; 1.0280x over previous
//
#include <hip/hip_runtime.h>
#include <math.h>

#define BB 4
#define LL 512
#define EMB 256
#define NH 8
#define HD 32
#define NB_ 3
#define CCN 10
#define NBKT 32
#define SCALE 0.17677669529663687f

typedef __bf16 bf16_t;
typedef __attribute__((ext_vector_type(8))) bf16_t bf16x8;
typedef __attribute__((ext_vector_type(4))) float f32x4;

__device__ __forceinline__ unsigned short f2b(float f) {
    unsigned int u = __float_as_uint(f);
    u += 0x7FFF + ((u >> 16) & 1);   // RNE
    return (unsigned short)(u >> 16);
}
__device__ __forceinline__ float b2f(unsigned short s) {
    return __uint_as_float(((unsigned int)s) << 16);
}
__device__ __forceinline__ unsigned pack2(float a, float b) {
    return (unsigned)f2b(a) | ((unsigned)f2b(b) << 16);
}
__device__ __forceinline__ int bm_of(int tq, int tk) {
    return (tq * tk != 0) ? ((tq - 1) * 3 + tk) : 0;
}
__device__ __forceinline__ unsigned long long shfl_up64(unsigned long long v, int d) {
    unsigned lo = (unsigned)__shfl_up((int)(unsigned)v, d, 64);
    unsigned hi = (unsigned)__shfl_up((int)(v >> 32), d, 64);
    return (((unsigned long long)hi) << 32) | lo;
}

// Stable counting sort of 512 tokens by type (4 types), 256 threads.
__device__ __forceinline__ void sort512(const int* __restrict__ tsb, int* spk,
                                        unsigned long long* wtll, int* msc, int tid) {
    int ty0 = tsb[2 * tid], ty1 = tsb[2 * tid + 1];
    unsigned long long pk = (1ULL << (16 * ty0)) + (1ULL << (16 * ty1));
    unsigned long long v = pk;
    int lane = tid & 63;
#pragma unroll
    for (int off = 1; off < 64; off <<= 1) {
        unsigned long long o = shfl_up64(v, off);
        if (lane >= off) v += o;
    }
    int w = tid >> 6;
    if (lane == 63) wtll[w] = v;
    __syncthreads();
    unsigned long long pre = 0, tot = 0;
#pragma unroll
    for (int i = 0; i < 4; i++) {
        unsigned long long xx = wtll[i];
        if (i < w) pre += xx;
        tot += xx;
    }
    v += pre;
    unsigned long long excl = v - pk;
    int c0 = (int)(tot & 0xFFFF), c1 = (int)((tot >> 16) & 0xFFFF);
    int c2 = (int)((tot >> 32) & 0xFFFF), c3 = (int)((tot >> 48) & 0xFFFF);
    int ub0 = 0, ub1 = c0, ub2 = c0 + c1, ub3 = c0 + c1 + c2;
    if (tid == 0) {
        int pc0 = (c0 + 31) & ~31, pc1 = (c1 + 31) & ~31, pc2 = (c2 + 31) & ~31, pc3 = (c3 + 31) & ~31;
        int pb1 = pc0, pb2 = pc0 + pc1, pb3 = pc0 + pc1 + pc2;
        msc[0] = 0;  msc[1] = pb1; msc[2] = pb2; msc[3] = pb3;
        msc[4] = ub0; msc[5] = ub1; msc[6] = ub2; msc[7] = ub3;
        msc[8] = c0; msc[9] = c1; msc[10] = c2; msc[11] = c3;
        msc[12] = (pb3 + pc3 + 63) & ~63;
    }
    int bases[4] = {ub0, ub1, ub2, ub3};
    int r0 = (int)((excl >> (16 * ty0)) & 0xFFFF);
    unsigned long long excl1 = excl + (1ULL << (16 * ty0));
    int r1 = (int)((excl1 >> (16 * ty1)) & 0xFFFF);
    spk[bases[ty0] + r0] = (ty0 << 16) | (2 * tid);
    spk[bases[ty1] + r1] = (ty1 << 16) | (2 * tid + 1);
    __syncthreads();
}

__device__ __forceinline__ void pad_lookup(const int* msc, int pos, int& real, int& upos, int& seg) {
    seg = (pos >= msc[1]) + (pos >= msc[2]) + (pos >= msc[3]);
    int r = pos - msc[seg];
    real = (r < msc[8 + seg]) ? 1 : 0;
    upos = msc[4 + seg] + r;
}

// ---------------- K1 (merged): QKV (g<384, self-sort + direct strided f32 W reads)
// + alpha-combine (384<=g<544) + mask scan (544<=g<672, plain flag stores)
// + sort-out (672<=g<676) + bucket table (g==676). ----------------
__global__ __launch_bounds__(256, 4) void k_main(
    const float* __restrict__ x, const int* __restrict__ ts,
    const float* __restrict__ Wq, const float* __restrict__ Wk, const float* __restrict__ Wv,
    const float* __restrict__ A1, const float* __restrict__ W1,
    const float* __restrict__ A2, const float* __restrict__ W2,
    const float* __restrict__ am,
    float* __restrict__ W1s, float* __restrict__ W2s,
    unsigned short* __restrict__ W1Tb, unsigned short* __restrict__ W2Tb,
    int* __restrict__ mfl,
    int* __restrict__ spkg, int* __restrict__ mscg, int* __restrict__ kpadg,
    short* __restrict__ tblg,
    unsigned short* __restrict__ qp, unsigned short* __restrict__ kp,
    unsigned short* __restrict__ vpT) {
    __shared__ int spk[LL];
    __shared__ unsigned long long wtll[4];
    __shared__ int msc[16];
    __shared__ __align__(16) unsigned short vt_l[128 * 33];

    int g = blockIdx.x, tid = threadIdx.x;

    if (g >= 384) {
        int gg = g - 384;
        if (gg < 160) {  // alpha-combine (consumed by k_attn, next launch)
            float* cmbf = (float*)vt_l;  // 4224 B <= 8448 B
            int idx = gg;
            const float* alpha = (idx < 80) ? A1 : A2;
            const float* W     = (idx < 80) ? W1 : W2;
            float* Ws          = (idx < 80) ? W1s : W2s;
            unsigned short* WT = (idx < 80) ? W1Tb : W2Tb;
            idx %= 80;
            int cc = idx / NH, h = idx % NH;
            float a0 = alpha[cc * NB_ * NH + 0 * NH + h];
            float a1 = alpha[cc * NB_ * NH + 1 * NH + h];
            float a2 = alpha[cc * NB_ * NH + 2 * NH + h];
            float mx = fmaxf(a0, fmaxf(a1, a2));
            float e0 = __expf(a0 - mx), e1 = __expf(a1 - mx), e2 = __expf(a2 - mx);
            float inv = 1.0f / (e0 + e1 + e2);
            e0 *= inv; e1 *= inv; e2 *= inv;
            for (int i = tid; i < HD * HD; i += 256) {
                int m = i >> 5, n = i & 31;
                float acc = e0 * W[((0 * NH + h) * HD + m) * HD + n]
                          + e1 * W[((1 * NH + h) * HD + m) * HD + n]
                          + e2 * W[((2 * NH + h) * HD + m) * HD + n];
                cmbf[m * 33 + n] = acc;
            }
            __syncthreads();
            for (int i = tid; i < HD * HD; i += 256) {
                int a = i >> 5, bq = i & 31;
                Ws[((cc * NH + h) * HD + a) * HD + bq] = cmbf[a * 33 + bq];
                WT[((size_t)(cc * NH + h) * HD + a) * HD + bq] = f2b(cmbf[bq * 33 + a]);
            }
            return;
        }
        if (gg < 288) {  // mask scan: per-block flag, plain store (no init needed)
            int* reds = (int*)wtll;
            int idx = gg - 160;
            const uint4* p = (const uint4*)am + (size_t)idx * 2048;
            unsigned o = 0;
#pragma unroll
            for (int j = 0; j < 8; j++) {
                uint4 v = p[tid + j * 256];
                o |= v.x | v.y | v.z | v.w;
            }
            int wv = __any(o != 0);
            if ((tid & 63) == 0) reds[tid >> 6] = wv;
            __syncthreads();
            if (tid == 0) mfl[idx] = reds[0] | reds[1] | reds[2] | reds[3];
            return;
        }
        if (gg < 292) {  // sort-out: spkg/mscg/kpadg for k_attn
            int b = gg - 288;
            sort512(ts + b * LL, spk, wtll, msc, tid);
            for (int i = tid; i < LL; i += 256) spkg[b * LL + i] = spk[i];
            if (tid < 16) mscg[b * 16 + tid] = msc[tid];
            int KT = msc[12];
            for (int pos = tid; pos < KT; pos += 256) {
                int real, upos, seg;
                pad_lookup(msc, pos, real, upos, seg);
                int orig = real ? (spk[upos] & 0xFFFF) : 0x3FF;
                kpadg[b * 640 + pos] = (seg << 20) | ((real ? upos : 0) << 10) | orig;
            }
            return;
        }
        // bucket table
        for (int d = tid; d < LL; d += 256) {
            int v;
            if (d < 8) v = d;
            else {
                double r = log((double)d / 8.0) / log(5.0);
                v = 8 + (int)(r * 8.0);
                if (v > 15) v = 15;
            }
            tblg[d] = (short)v;
        }
        return;
    }

    // ---------------- QKV block ----------------
    int ns = g % 6, gb = g / 6;
    int b = gb >> 4, tb = gb & 15, i0 = tb * 32;
    int which = ns >> 1, nh = ns & 1;
    int wave = tid >> 6, lane = tid & 63, quad = lane >> 4, col = lane & 15;

    // self-sort (deterministic; identical to sort-out blocks' result)
    sort512(ts + b * LL, spk, wtll, msc, tid);

    bf16x8 afr[2][8];
#pragma unroll
    for (int mt = 0; mt < 2; mt++) {
        int orig = spk[i0 + mt * 16 + col] & 0xFFFF;
        const float* xr = &x[(size_t)(b * LL + orig) * EMB];
#pragma unroll
        for (int kc = 0; kc < 8; kc++) {
            float4 v0 = *(const float4*)&xr[kc * 32 + quad * 8];
            float4 v1 = *(const float4*)&xr[kc * 32 + quad * 8 + 4];
            uint4 up;
            up.x = pack2(v0.x, v0.y); up.y = pack2(v0.z, v0.w);
            up.z = pack2(v1.x, v1.y); up.w = pack2(v1.z, v1.w);
            afr[mt][kc] = *(bf16x8*)&up;
        }
    }
    int t_start = spk[i0] >> 16, t_end = spk[i0 + 31] >> 16;
    unsigned short* outp = (which == 0) ? qp : kp;
    const float* wmat = (which == 0) ? Wq : (which == 1) ? Wk : Wv;

    int n_0 = nh * 128 + (wave * 2 + 0) * 16 + col;   // output column for b0
    // b1 column = n_0 + 16

    for (int ty = t_start; ty <= t_end; ty++) {
        const float* wty = wmat + (size_t)ty * EMB * EMB;
        // per-lane strided column base: element j of kc-fragment = wcol[kc*32*EMB + j*EMB]
        const float* wc0 = wty + (size_t)(quad * 8) * EMB + n_0;
        const float* wc1 = wc0 + 16;
        f32x4 acc[2][2];
#pragma unroll
        for (int mt = 0; mt < 2; mt++)
#pragma unroll
            for (int nt = 0; nt < 2; nt++) acc[mt][nt] = (f32x4){0.f, 0.f, 0.f, 0.f};
#pragma unroll
        for (int kc = 0; kc < 8; kc++) {
            const float* p0 = wc0 + (size_t)kc * 32 * EMB;
            const float* p1 = wc1 + (size_t)kc * 32 * EMB;
            float f0[8], f1[8];
#pragma unroll
            for (int j = 0; j < 8; j++) { f0[j] = p0[j * EMB]; f1[j] = p1[j * EMB]; }
            uint4 u0, u1;
            u0.x = pack2(f0[0], f0[1]); u0.y = pack2(f0[2], f0[3]);
            u0.z = pack2(f0[4], f0[5]); u0.w = pack2(f0[6], f0[7]);
            u1.x = pack2(f1[0], f1[1]); u1.y = pack2(f1[2], f1[3]);
            u1.z = pack2(f1[4], f1[5]); u1.w = pack2(f1[6], f1[7]);
            bf16x8 b0 = *(bf16x8*)&u0;
            bf16x8 b1 = *(bf16x8*)&u1;
            acc[0][0] = __builtin_amdgcn_mfma_f32_16x16x32_bf16(afr[0][kc], b0, acc[0][0], 0, 0, 0);
            acc[0][1] = __builtin_amdgcn_mfma_f32_16x16x32_bf16(afr[0][kc], b1, acc[0][1], 0, 0, 0);
            acc[1][0] = __builtin_amdgcn_mfma_f32_16x16x32_bf16(afr[1][kc], b0, acc[1][0], 0, 0, 0);
            acc[1][1] = __builtin_amdgcn_mfma_f32_16x16x32_bf16(afr[1][kc], b1, acc[1][1], 0, 0, 0);
        }
        if (which < 2) {
#pragma unroll
            for (int mt = 0; mt < 2; mt++)
#pragma unroll
                for (int r = 0; r < 4; r++) {
                    int tokloc = mt * 16 + quad * 4 + r;
                    int tty = spk[i0 + tokloc] >> 16;
                    if (tty != ty) continue;
#pragma unroll
                    for (int nt = 0; nt < 2; nt++) {
                        int n = n_0 + nt * 16;
                        int h = n >> 5, d = n & 31;
                        outp[((size_t)(b * NH + h) * LL + i0 + tokloc) * HD + d] = f2b(acc[mt][nt][r]);
                    }
                }
        } else {
#pragma unroll
            for (int mt = 0; mt < 2; mt++)
#pragma unroll
                for (int nt = 0; nt < 2; nt++) {
                    int ln = (wave * 2 + nt) * 16 + col;
#pragma unroll
                    for (int r = 0; r < 4; r++)
                        vt_l[ln * 33 + mt * 16 + quad * 4 + r] = f2b(acc[mt][nt][r]);
                }
            __syncthreads();
            int ub = msc[4 + ty], cnt = msc[8 + ty], pb = msc[ty];
            int lo = ub - i0; if (lo < 0) lo = 0;
            int hi = ub + cnt - i0; if (hi > 32) hi = 32;
            int run = hi - lo;
            int pbase = pb + i0 + lo - ub;
            int rowbase = b * 256 + nh * 128;
            int t32 = tid & 31;
            if (t32 < run) {
                for (int rr = tid >> 5; rr < 128; rr += 8)
                    vpT[(size_t)(rowbase + rr) * 640 + pbase + t32] = vt_l[rr * 33 + lo + t32];
            }
            __syncthreads();
        }
    }
}

// ---------------- K2: attention core, 512 threads / 8 waves (fused softmax when mask==0) ----------------
#define SCP 648
#define OFF_UN   20736
#define OFF_QTB  29184
#define OFF_KPAD 33536
#define OFF_TBL  36096
#define OFF_RPL  37120
#define OFF_QOR  38400
#define OFF_QTY  38464
#define OFF_INV  38528
#define OFF_PSUM 38592
#define SM_TOTAL 39104
__global__ __launch_bounds__(512, 8) void k_attn(
    const unsigned short* __restrict__ qp, const unsigned short* __restrict__ kp,
    const unsigned short* __restrict__ vpT,
    const int* __restrict__ spkg, const int* __restrict__ mscg, const int* __restrict__ kpadg,
    const short* __restrict__ tblg,
    const float* __restrict__ rp, const float* __restrict__ am,
    const float* __restrict__ W1s, const float* __restrict__ W2s,
    const unsigned short* __restrict__ W1Tb, const unsigned short* __restrict__ W2Tb,
    const int* __restrict__ mfl, float* __restrict__ ctx) {
    __shared__ __align__(16) char smem[SM_TOTAL];
    __shared__ int msk_s;
    unsigned short* scu = (unsigned short*)smem;
    unsigned short* qstb = (unsigned short*)(smem + OFF_UN);   // [16*40]
    float* sb   = (float*)(smem + OFF_UN);                     // [16*132] (aliases qstb, dead after qt)
    unsigned short* qtb = (unsigned short*)(smem + OFF_QTB);   // [16*136] / later sbb
    unsigned short* sbb = (unsigned short*)(smem + OFF_QTB);
    int*   kpad = (int*)(smem + OFF_KPAD);                     // [640]
    short* tbl  = (short*)(smem + OFF_TBL);
    float* rp_l = (float*)(smem + OFF_RPL);
    int*   qor_l = (int*)(smem + OFF_QOR);
    int*   qty_l = (int*)(smem + OFF_QTY);
    float* inv_l = (float*)(smem + OFF_INV);
    float* psum = (float*)(smem + OFF_PSUM);                   // [128] per-wave row sums

    int blk = blockIdx.x;
    int b = blk >> 8, h = (blk >> 5) & 7, q16 = blk & 31;
    int i0q = q16 * 16;
    int tid = threadIdx.x;
    int wave = tid >> 6, lane = tid & 63, quad = lane >> 4, col = lane & 15;
    int bh = b * NH + h;

    int KT = mscg[b * 16 + 12];
    if (wave == 0) {
        int v = mfl[lane] | mfl[64 + lane];
        int anyv = __any(v != 0);
        if (lane == 0) msk_s = anyv;
    }
    if (tid < 16) {
        int v = spkg[b * LL + i0q + tid];
        qor_l[tid] = v & 0xFFFF; qty_l[tid] = v >> 16;
    }
    if (tid < (KT >> 2)) ((int4*)kpad)[tid] = ((const int4*)(kpadg + b * 640))[tid];
    if (tid < 256) ((int*)tbl)[tid] = ((const int*)tblg)[tid];   // 512 shorts = 256 ints
    for (int i = tid; i < CCN * NBKT; i += 512) rp_l[i] = rp[i * NH + h];
    if (tid < 256) {   // stage 16 q rows (bf16, pitch 40)
        int q = tid >> 4, m2 = (tid & 15) * 2;
        ((unsigned*)qstb)[q * 20 + (tid & 15)] =
            *(const unsigned*)&qp[((size_t)bh * LL + i0q + q) * HD + m2];
    }
    __syncthreads();

    int qor_r[4], qty_r[4];
#pragma unroll
    for (int r = 0; r < 4; r++) { qor_r[r] = qor_l[quad * 4 + r]; qty_r[r] = qty_l[quad * 4 + r]; }
    bool uniq = (qty_l[0] == qty_l[15]);
    int tqu = qty_l[0];
    // tokens are sorted by type, so a 16-row tile is almost always 1 or 2 contiguous types
    int tA = qty_l[0], tB = qty_l[15];
    bool two = false;
    if (!uniq) {
        two = true;
#pragma unroll
        for (int i = 0; i < 16; i++) {
            int t = qty_l[i];
            two = two && (t == tA || t == tB);
        }
    }
    int mz = (msk_s == 0);

    // ---- qt: 8 sub-problems, one per wave ----
    if (uniq) {
        int tk = wave >> 1, nhf = wave & 1;
        int bmv = bm_of(tqu, tk);
        bf16x8 a = *(const bf16x8*)&qstb[col * 40 + quad * 8];
        bf16x8 bb = *(const bf16x8*)&W1Tb[((size_t)(bmv * NH + h) * HD + nhf * 16 + col) * HD + quad * 8];
        f32x4 d = {0.f, 0.f, 0.f, 0.f};
        d = __builtin_amdgcn_mfma_f32_16x16x32_bf16(a, bb, d, 0, 0, 0);
#pragma unroll
        for (int r = 0; r < 4; r++)
            qtb[(quad * 4 + r) * 136 + tk * 32 + nhf * 16 + col] = f2b(d[r]);
    } else if (two) {
        int tk = wave >> 1, nhf = wave & 1;
        bf16x8 a = *(const bf16x8*)&qstb[col * 40 + quad * 8];
        bf16x8 bA = *(const bf16x8*)&W1Tb[((size_t)(bm_of(tA, tk) * NH + h) * HD + nhf * 16 + col) * HD + quad * 8];
        bf16x8 bBv = *(const bf16x8*)&W1Tb[((size_t)(bm_of(tB, tk) * NH + h) * HD + nhf * 16 + col) * HD + quad * 8];
        f32x4 dA = {0.f, 0.f, 0.f, 0.f};
        f32x4 dB = {0.f, 0.f, 0.f, 0.f};
        dA = __builtin_amdgcn_mfma_f32_16x16x32_bf16(a, bA, dA, 0, 0, 0);
        dB = __builtin_amdgcn_mfma_f32_16x16x32_bf16(a, bBv, dB, 0, 0, 0);
#pragma unroll
        for (int r = 0; r < 4; r++) {
            float val = (qty_r[r] == tA) ? dA[r] : dB[r];
            qtb[(quad * 4 + r) * 136 + tk * 32 + nhf * 16 + col] = f2b(val);
        }
    } else {
        for (int i = tid; i < 16 * 128; i += 512) {
            int q = i >> 7, r = i & 127, tk = r >> 5, n = r & 31;
            int bmv = bm_of(qty_l[q], tk);
            const float* wb = &W1s[((bmv * NH + h) * HD) * HD + n];
            float acc = 0.f;
#pragma unroll
            for (int m = 0; m < HD; m++) acc += b2f(qstb[q * 40 + m]) * wb[m * HD];
            qtb[q * 136 + tk * 32 + n] = f2b(acc);
        }
    }
    __syncthreads();

    // ---- pass 1: scores, tiles strided across 8 waves ----
    const float* amb = am + (size_t)b * LL * LL;
    int ntiles = KT >> 4;
    if (mz) {
        float rs[4] = {0.f, 0.f, 0.f, 0.f};
        int tqm_r[4], tqz_r[4];
#pragma unroll
        for (int r = 0; r < 4; r++) { tqm_r[r] = (qty_r[r] - 1) * 3; tqz_r[r] = (qty_r[r] != 0); }
        for (int tile = wave; tile < ntiles; tile += 8) {
            int kb = tile * 16;
            int kv0 = kpad[kb];
            if ((kv0 & 0x3FF) == 0x3FF) {
#pragma unroll
                for (int r = 0; r < 4; r++) scu[(quad * 4 + r) * SCP + kb + col] = 0;
                continue;
            }
            int tkt = kv0 >> 20;
            int kpi = kb + col;
            int kv = kpad[kpi];
            int ko = kv & 0x3FF;
            int upos = (kv >> 10) & 0x3FF;
            bool real = (ko != 0x3FF);
            bf16x8 bfr;
            if (real) bfr = *(const bf16x8*)&kp[((size_t)bh * LL + upos) * HD + quad * 8];
            else { uint4 z = make_uint4(0, 0, 0, 0); bfr = *(bf16x8*)&z; }
            bf16x8 a = *(const bf16x8*)&qtb[col * 136 + tkt * 32 + quad * 8];
            f32x4 d = {0.f, 0.f, 0.f, 0.f};
            d = __builtin_amdgcn_mfma_f32_16x16x32_bf16(a, bfr, d, 0, 0, 0);
            if (!real) {
#pragma unroll
                for (int r = 0; r < 4; r++) scu[(quad * 4 + r) * SCP + kpi] = 0;
            } else {
#pragma unroll
                for (int r = 0; r < 4; r++) {
                    int q = quad * 4 + r;
                    int qo = qor_r[r];
                    int dd = qo - ko;
                    int ad = dd < 0 ? -dd : dd;
                    int bk = (dd < 0 ? 16 : 0) + (int)tbl[ad];
                    int bmv = (tqz_r[r] && tkt) ? tqm_r[r] + tkt : 0;
                    float sv = d[r] * SCALE + rp_l[bmv * NBKT + bk];
                    float e = __expf(sv);
                    scu[q * SCP + kpi] = f2b(e);
                    rs[r] += e;
                }
            }
        }
#pragma unroll
        for (int off = 1; off < 16; off <<= 1) {
#pragma unroll
            for (int r = 0; r < 4; r++) rs[r] += __shfl_xor(rs[r], off, 16);
        }
        if (col == 0) {
#pragma unroll
            for (int r = 0; r < 4; r++) psum[wave * 16 + quad * 4 + r] = rs[r];
        }
    } else {
        for (int tile = wave; tile < ntiles; tile += 8) {
            int kb = tile * 16;
            int kv0 = kpad[kb];
            if ((kv0 & 0x3FF) == 0x3FF) {
#pragma unroll
                for (int r = 0; r < 4; r++) scu[(quad * 4 + r) * SCP + kb + col] = 0xFF80;
                continue;
            }
            int tkt = kv0 >> 20;
            int kpi = kb + col;
            int kv = kpad[kpi];
            int ko = kv & 0x3FF;
            int upos = (kv >> 10) & 0x3FF;
            bool real = (ko != 0x3FF);
            bf16x8 bfr;
            if (real) bfr = *(const bf16x8*)&kp[((size_t)bh * LL + upos) * HD + quad * 8];
            else { uint4 z = make_uint4(0, 0, 0, 0); bfr = *(bf16x8*)&z; }
            bf16x8 a = *(const bf16x8*)&qtb[col * 136 + tkt * 32 + quad * 8];
            f32x4 d = {0.f, 0.f, 0.f, 0.f};
            d = __builtin_amdgcn_mfma_f32_16x16x32_bf16(a, bfr, d, 0, 0, 0);
            if (!real) {
#pragma unroll
                for (int r = 0; r < 4; r++) scu[(quad * 4 + r) * SCP + kpi] = 0xFF80;
            } else {
#pragma unroll
                for (int r = 0; r < 4; r++) {
                    int q = quad * 4 + r;
                    int qo = qor_r[r];
                    int dd = qo - ko;
                    int ad = dd < 0 ? -dd : dd;
                    int bk = (dd < 0 ? 16 : 0) + (int)tbl[ad];
                    float sv = d[r] * SCALE + rp_l[bm_of(qty_r[r], tkt) * NBKT + bk];
                    sv += amb[(size_t)qo * LL + ko];
                    scu[q * SCP + kpi] = f2b(sv);
                }
            }
        }
    }
    __syncthreads();

    // ---- pass 2: softmax finish ----
    if (mz) {
        if (tid < 16) {
            float s = 0.f;
#pragma unroll
            for (int w = 0; w < 8; w++) s += psum[w * 16 + tid];
            inv_l[tid] = 1.0f / s;
        }
    } else if (tid < 256) {
        int gq = tid >> 4, t16 = tid & 15;
        float mx = -1e30f;
        for (int kk = t16; kk < KT; kk += 16) mx = fmaxf(mx, b2f(scu[gq * SCP + kk]));
#pragma unroll
        for (int off = 1; off < 16; off <<= 1) mx = fmaxf(mx, __shfl_xor(mx, off, 16));
        float sum = 0.f;
        for (int kk = t16; kk < KT; kk += 16) {
            int idx = gq * SCP + kk;
            float e = __expf(b2f(scu[idx]) - mx);
            scu[idx] = f2b(e); sum += e;
        }
#pragma unroll
        for (int off = 1; off < 16; off <<= 1) sum += __shfl_xor(sum, off, 16);
        if (t16 == 0) inv_l[gq] = 1.0f / sum;
    }
    __syncthreads();

    // ---- pass 3: PV via MFMA; wave pair (seg, seg+4) splits segment seg's 32-groups
    //      (even/odd). Pair-reduce through sb/sbb with one extra barrier. ----
    const unsigned short* vbase = &vpT[(size_t)(b * 256 + h * 32) * 640];
    f32x4 accv[2];
    accv[0] = (f32x4){0.f, 0.f, 0.f, 0.f};
    accv[1] = (f32x4){0.f, 0.f, 0.f, 0.f};
    {
        int seg = wave & 3, halfp = wave >> 2;
        int pb = mscg[b * 16 + seg];         // padded base of segment
        int cnt = mscg[b * 16 + 8 + seg];    // real count of segment
        int g0 = pb >> 5, g1 = (pb + cnt + 31) >> 5;
        for (int gg = g0 + halfp; gg < g1; gg += 2) {
            int loc = gg << 5;
            bf16x8 a = *(const bf16x8*)&scu[col * SCP + loc + quad * 8];
            bf16x8 b0 = *(const bf16x8*)&vbase[(size_t)col * 640 + loc + quad * 8];
            bf16x8 b1 = *(const bf16x8*)&vbase[(size_t)(col + 16) * 640 + loc + quad * 8];
            accv[0] = __builtin_amdgcn_mfma_f32_16x16x32_bf16(a, b0, accv[0], 0, 0, 0);
            accv[1] = __builtin_amdgcn_mfma_f32_16x16x32_bf16(a, b1, accv[1], 0, 0, 0);
        }
    }
    // waves 0-3 deposit partials (sb aliases qstb — dead); waves 4-7 add + emit bf16
    if (wave < 4) {
#pragma unroll
        for (int hh = 0; hh < 2; hh++)
#pragma unroll
            for (int r = 0; r < 4; r++) {
                int q = quad * 4 + r, n = col + 16 * hh;
                sb[q * 132 + wave * 32 + n] = accv[hh][r];
            }
    }
    __syncthreads();
    if (wave >= 4) {
        int seg = wave - 4;
#pragma unroll
        for (int hh = 0; hh < 2; hh++)
#pragma unroll
            for (int r = 0; r < 4; r++) {
                int q = quad * 4 + r, n = col + 16 * hh;
                float fin = sb[q * 132 + seg * 32 + n] + accv[hh][r];
                sb[q * 132 + seg * 32 + n] = fin;
                sbb[q * 136 + seg * 32 + n] = f2b(fin);
            }
    }
    __syncthreads();

    // ---- ctx epilogue ----
    if (uniq) {
        if (wave < 2) {
            int mhf = wave;
            f32x4 d = {0.f, 0.f, 0.f, 0.f};
#pragma unroll
            for (int tk = 0; tk < 4; tk++) {
                int bmv = bm_of(tqu, tk);
                bf16x8 a = *(const bf16x8*)&sbb[col * 136 + tk * 32 + quad * 8];
                bf16x8 bb = *(const bf16x8*)&W2Tb[((size_t)(bmv * NH + h) * HD + mhf * 16 + col) * HD + quad * 8];
                d = __builtin_amdgcn_mfma_f32_16x16x32_bf16(a, bb, d, 0, 0, 0);
            }
#pragma unroll
            for (int r = 0; r < 4; r++) {
                int q = quad * 4 + r;
                ctx[((size_t)(b * LL + qor_l[q])) * EMB + h * HD + mhf * 16 + col] = d[r] * inv_l[q];
            }
        }
    } else if (two) {
        if (wave < 4) {
            // waves 0,1 -> type tA (halves 0,1); waves 2,3 -> type tB (halves 0,1)
            int myT = (wave < 2) ? tA : tB;
            int mhf = wave & 1;
            f32x4 d = {0.f, 0.f, 0.f, 0.f};
#pragma unroll
            for (int tk = 0; tk < 4; tk++) {
                int bmv = bm_of(myT, tk);
                bf16x8 a = *(const bf16x8*)&sbb[col * 136 + tk * 32 + quad * 8];
                bf16x8 bb = *(const bf16x8*)&W2Tb[((size_t)(bmv * NH + h) * HD + mhf * 16 + col) * HD + quad * 8];
                d = __builtin_amdgcn_mfma_f32_16x16x32_bf16(a, bb, d, 0, 0, 0);
            }
#pragma unroll
            for (int r = 0; r < 4; r++) {
                int q = quad * 4 + r;
                if (qty_l[q] == myT)
                    ctx[((size_t)(b * LL + qor_l[q])) * EMB + h * HD + mhf * 16 + col] = d[r] * inv_l[q];
            }
        }
    } else if (tid < 256) {
        int m = tid & 31, qq = tid >> 5;
#pragma unroll
        for (int rep = 0; rep < 2; rep++) {
            int qi = qq + 8 * rep;
            int tq = qty_l[qi];
            float acc = 0.f;
#pragma unroll
            for (int tk2 = 0; tk2 < 4; tk2++) {
                int bmv = bm_of(tq, tk2);
                const float* wb = &W2s[((bmv * NH + h) * HD) * HD + m];
                const float* sbp = &sb[qi * 132 + tk2 * 32];
                for (int n = 0; n < HD; n++) acc += sbp[n] * wb[n * HD];
            }
            int qo = qor_l[qi];
            ctx[((size_t)(b * LL + qo)) * EMB + h * HD + m] = acc * inv_l[qi];
        }
    }
}

// ---------------- K3: residual + LayerNorm (wave-per-token, barrier-free) ----------------
__global__ void k_ln(const float* __restrict__ ctx, const float* __restrict__ x,
                     const float* __restrict__ gamma, const float* __restrict__ beta,
                     float* __restrict__ out) {
    int wave = threadIdx.x >> 6, lane = threadIdx.x & 63;
    int tok = blockIdx.x * 4 + wave;
    size_t base = (size_t)tok * EMB + lane * 4;
    float4 c = *(const float4*)&ctx[base];
    float4 xi = *(const float4*)&x[base];
    float4 v;
    v.x = c.x + xi.x; v.y = c.y + xi.y; v.z = c.z + xi.z; v.w = c.w + xi.w;
    float s = v.x + v.y + v.z + v.w;
    float s2 = v.x * v.x + v.y * v.y + v.z * v.z + v.w * v.w;
#pragma unroll
    for (int off = 1; off < 64; off <<= 1) {
        s += __shfl_xor(s, off, 64);
        s2 += __shfl_xor(s2, off, 64);
    }
    float mu = s * (1.0f / EMB);
    float var = s2 * (1.0f / EMB) - mu * mu;
    float r = rsqrtf(var + 1e-12f);
    float4 gg = *(const float4*)&gamma[lane * 4];
    float4 bb = *(const float4*)&beta[lane * 4];
    float4 o;
    o.x = (v.x - mu) * r * gg.x + bb.x;
    o.y = (v.y - mu) * r * gg.y + bb.y;
    o.z = (v.z - mu) * r * gg.z + bb.z;
    o.w = (v.w - mu) * r * gg.w + bb.w;
    *(float4*)&out[base] = o;
}

extern "C" void kernel_launch(void* const* d_in, const int* in_sizes, int n_in,
                              void* d_out, int out_size, void* d_ws, size_t ws_size,
                              hipStream_t stream) {
    const float* x  = (const float*)d_in[0];
    const float* am = (const float*)d_in[1];
    const int*   ts = (const int*)d_in[2];
    const float* Wq = (const float*)d_in[3];
    const float* Wk = (const float*)d_in[4];
    const float* Wv = (const float*)d_in[5];
    const float* W1 = (const float*)d_in[6];
    const float* a1 = (const float*)d_in[7];
    const float* W2 = (const float*)d_in[8];
    const float* a2 = (const float*)d_in[9];
    const float* rp = (const float*)d_in[10];
    const float* g  = (const float*)d_in[11];
    const float* be = (const float*)d_in[12];
    float* out = (float*)d_out;

    float* ws  = (float*)d_ws;
    float* W1s = ws;                                        // 81920 f
    float* W2s = ws + 81920;                                // -> 163840
    unsigned short* W1Tb = (unsigned short*)(ws + 163840);  // 40960 f
    unsigned short* W2Tb = (unsigned short*)(ws + 204800);  // 40960 f -> 245760
    int* mfl  = (int*)(ws + 245760);                        // 128 mask flags (plain stores, no init)
    int* spkg = (int*)(ws + 246016);                        // 2048 i -> 248064
    int* mscg = (int*)(ws + 248064);                        // 64 i -> 248128
    int* kpadg = (int*)(ws + 248128);                       // 2560 i -> 250688
    short* tblg = (short*)(ws + 250688);                    // 512 s -> 250944
    unsigned short* qp = (unsigned short*)(ws + 250944);
    unsigned short* kp = qp + BB * NH * LL * HD;
    unsigned short* vpT = kp + BB * NH * LL * HD;
    float* ctx = (float*)(vpT + BB * 256 * 640);

    hipLaunchKernelGGL(k_main, dim3(677), dim3(256), 0, stream,
                       x, ts, Wq, Wk, Wv, a1, W1, a2, W2, am,
                       W1s, W2s, W1Tb, W2Tb, mfl, spkg, mscg, kpadg, tblg,
                       qp, kp, vpT);
    hipLaunchKernelGGL(k_attn, dim3(BB * NH * 32), dim3(512), 0, stream,
                       qp, kp, vpT, spkg, mscg, kpadg, tblg, rp, am, W1s, W2s, W1Tb, W2Tb,
                       mfl, ctx);
    hipLaunchKernelGGL(k_ln, dim3(BB * LL / 4), dim3(256), 0, stream, ctx, x, g, be, out);
}